// Round 3
// baseline (600.168 us; speedup 1.0000x reference)
//
#include <hip/hip_runtime.h>

#define B 4
#define L 2048
#define C 64
#define NCH 256
#define TQ1 8          // fine chunk length
#define S1 256         // fine chunks per chain
#define GF 8           // fine chunks per coarse chunk
#define S2 32           // coarse chunks

// ---- LDS swizzle helpers (16B units). Conflict-free by construction:
// A-slab: 2 planes (re/im), 64 chains x 16 units/plane.
__device__ __forceinline__ int posA(int p, int c, int u) {
    return p * 1024 + c * 16 + (u ^ (c & 15));
}
// Prefix slab: interleaved c64, 64 chains x 32 units.
__device__ __forceinline__ int posPF(int c, int u) {
    return c * 32 + (u ^ (c & 31));
}

// ======== Phase 1: fine chunk summaries (chain-per-lane) ========
// Backward over t: q += P @ x_t ; P = P @ A_t  => P = A_end..A_start, q = zero-carry end value.
__global__ __launch_bounds__(64) void k_sum(
    const float* __restrict__ Are, const float* __restrict__ Aim,
    const float* __restrict__ Xre, const float* __restrict__ Xim,
    float2* __restrict__ sumP, float2* __restrict__ sumQ)
{
    __shared__ float4 lds[2048];               // 32 KB A-slab
    const int lane = threadIdx.x;
    const int blk  = blockIdx.x;
    const int b = blk >> 8, s1 = blk & 255;

    float Pre[8][8], Pim[8][8];
#pragma unroll
    for (int r = 0; r < 8; ++r)
#pragma unroll
        for (int c = 0; c < 8; ++c) { Pre[r][c] = (r == c) ? 1.f : 0.f; Pim[r][c] = 0.f; }
    float qre[8], qim[8];
#pragma unroll
    for (int r = 0; r < 8; ++r) { qre[r] = 0.f; qim[r] = 0.f; }

#pragma unroll 1
    for (int tt = TQ1 - 1; tt >= 0; --tt) {
        const int t = s1 * TQ1 + tt;
        const long fb = ((long)(b * L + t)) * C;
        // ---- stage A slab (coalesced load -> swizzled LDS store)
        {
            const float4* g0 = (const float4*)(Are + fb * 64);
            float4 v[16];
#pragma unroll
            for (int io = 0; io < 16; ++io) v[io] = g0[io * 64 + lane];
#pragma unroll
            for (int io = 0; io < 16; ++io)
                lds[posA(0, io * 4 + (lane >> 4), lane & 15)] = v[io];
            const float4* g1 = (const float4*)(Aim + fb * 64);
#pragma unroll
            for (int io = 0; io < 16; ++io) v[io] = g1[io * 64 + lane];
#pragma unroll
            for (int io = 0; io < 16; ++io)
                lds[posA(1, io * 4 + (lane >> 4), lane & 15)] = v[io];
        }
        // ---- x direct per-lane global loads
        float xr[8], xi[8];
        {
            const float4* gx = (const float4*)(Xre + fb * 8) + lane * 2;
            float4 a = gx[0], bb = gx[1];
            xr[0]=a.x; xr[1]=a.y; xr[2]=a.z; xr[3]=a.w; xr[4]=bb.x; xr[5]=bb.y; xr[6]=bb.z; xr[7]=bb.w;
            const float4* gy = (const float4*)(Xim + fb * 8) + lane * 2;
            a = gy[0]; bb = gy[1];
            xi[0]=a.x; xi[1]=a.y; xi[2]=a.z; xi[3]=a.w; xi[4]=bb.x; xi[5]=bb.y; xi[6]=bb.z; xi[7]=bb.w;
        }
        // ---- q += P @ x_t (P still the suffix product A_end..A_{t+1})
#pragma unroll
        for (int r = 0; r < 8; ++r) {
            float nr = 0.f, ni = 0.f;
#pragma unroll
            for (int k = 0; k < 8; ++k) {
                nr += Pre[r][k] * xr[k] - Pim[r][k] * xi[k];
                ni += Pre[r][k] * xi[k] + Pim[r][k] * xr[k];
            }
            qre[r] += nr; qim[r] += ni;
        }
        // ---- P = P @ A_t, processed in two 4-row halves (in-place per row)
#pragma unroll
        for (int h = 0; h < 2; ++h) {
            float accre[4][8], accim[4][8];
#pragma unroll
            for (int rr = 0; rr < 4; ++rr)
#pragma unroll
                for (int c = 0; c < 8; ++c) { accre[rr][c] = 0.f; accim[rr][c] = 0.f; }
#pragma unroll
            for (int k = 0; k < 8; ++k) {
                const float4 e0 = lds[posA(0, lane, 2 * k)];
                const float4 e1 = lds[posA(0, lane, 2 * k + 1)];
                const float4 f0 = lds[posA(1, lane, 2 * k)];
                const float4 f1 = lds[posA(1, lane, 2 * k + 1)];
                const float are[8] = {e0.x,e0.y,e0.z,e0.w,e1.x,e1.y,e1.z,e1.w};
                const float aim[8] = {f0.x,f0.y,f0.z,f0.w,f1.x,f1.y,f1.z,f1.w};
#pragma unroll
                for (int rr = 0; rr < 4; ++rr) {
                    const float pr = Pre[h * 4 + rr][k], pi = Pim[h * 4 + rr][k];
#pragma unroll
                    for (int c = 0; c < 8; ++c) {
                        accre[rr][c] += pr * are[c] - pi * aim[c];
                        accim[rr][c] += pr * aim[c] + pi * are[c];
                    }
                }
            }
#pragma unroll
            for (int rr = 0; rr < 4; ++rr)
#pragma unroll
                for (int c = 0; c < 8; ++c) {
                    Pre[h * 4 + rr][c] = accre[rr][c];
                    Pim[h * 4 + rr][c] = accim[rr][c];
                }
        }
    }
    // ---- store summary: rows of P + q  (layout: [s1][n][r][8 c64])
    const int n = b * 64 + lane;
    float4* dp = (float4*)(sumP + ((long)s1 * 256 + n) * 64);
#pragma unroll
    for (int r = 0; r < 8; ++r)
#pragma unroll
        for (int s = 0; s < 4; ++s)
            dp[r * 4 + s] = make_float4(Pre[r][2*s], Pim[r][2*s], Pre[r][2*s+1], Pim[r][2*s+1]);
    float4* dq = (float4*)(sumQ + ((long)s1 * 256 + n) * 8);
#pragma unroll
    for (int s = 0; s < 4; ++s)
        dq[s] = make_float4(qre[2*s], qim[2*s], qre[2*s+1], qim[2*s+1]);
}

// ======== Phase 2a: combine 8 fine -> coarse; store prefixes IN-PLACE over sumP/sumQ ========
// Row-ownership: lane = (c8 chain-in-group, r row). M kept in LDS (swizzled).
__global__ __launch_bounds__(64) void k_comb(
    float2* sumP, float2* sumQ,                       // aliased read+write (prefixes)
    float2* __restrict__ sumP2, float2* __restrict__ sumQ2)
{
    __shared__ float4 M[256];                          // 8 chains x 8 rows x 4 units
    __shared__ float2 ql[64];
    const int lane = threadIdx.x;
    const int c8 = lane >> 3, r = lane & 7;
    const int blk = blockIdx.x;
    const int s2 = blk >> 5, g = blk & 31;
    const int n = g * 8 + c8;

    // M = I
#pragma unroll
    for (int s = 0; s < 4; ++s)
        M[c8 * 32 + ((r * 4 + s) ^ c8)] =
            make_float4((2*s == r) ? 1.f : 0.f, 0.f, (2*s+1 == r) ? 1.f : 0.f, 0.f);
    float q2r[8], q2i[8];
#pragma unroll
    for (int k = 0; k < 8; ++k) { q2r[k] = 0.f; q2i[k] = 0.f; }
    float mrn[8], min_[8];

#pragma unroll 1
    for (int j = 0; j < GF; ++j) {
        const long rowIdx = ((long)(s2 * 8 + j) * 256 + n) * 8 + r;
        const float4* gp = (const float4*)(sumP + rowIdx * 8);
        const float4 p0 = gp[0], p1 = gp[1], p2 = gp[2], p3 = gp[3];
        const float2 qf = sumQ[rowIdx];
        const float pfr[8] = {p0.x,p0.z,p1.x,p1.z,p2.x,p2.z,p3.x,p3.z};
        const float pfi[8] = {p0.y,p0.w,p1.y,p1.w,p2.y,p2.w,p3.y,p3.w};
        // store prefixes (old M row r, old q2[r]) in place
        float4 om[4];
#pragma unroll
        for (int s = 0; s < 4; ++s) om[s] = M[c8 * 32 + ((r * 4 + s) ^ c8)];
        float4* gout = (float4*)(sumP + rowIdx * 8);
#pragma unroll
        for (int s = 0; s < 4; ++s) gout[s] = om[s];
        sumQ[rowIdx] = make_float2(q2r[r], q2i[r]);
        // q2 = PF_j @ q2 + qF_j : own scalar then replicate
        float nr = qf.x, ni = qf.y;
#pragma unroll
        for (int k = 0; k < 8; ++k) {
            nr += pfr[k] * q2r[k] - pfi[k] * q2i[k];
            ni += pfr[k] * q2i[k] + pfi[k] * q2r[k];
        }
        ql[lane] = make_float2(nr, ni);
        const float4* qv = (const float4*)ql;
#pragma unroll
        for (int s = 0; s < 4; ++s) {
            const float4 u = qv[c8 * 4 + s];
            q2r[2*s] = u.x; q2i[2*s] = u.y; q2r[2*s+1] = u.z; q2i[2*s+1] = u.w;
        }
        // M = PF_j @ M : new row r = sum_k PF[r][k] * M[k][:]
#pragma unroll
        for (int c = 0; c < 8; ++c) { mrn[c] = 0.f; min_[c] = 0.f; }
#pragma unroll
        for (int k = 0; k < 8; ++k) {
            const float4 m0 = M[c8 * 32 + ((k * 4 + 0) ^ c8)];
            const float4 m1 = M[c8 * 32 + ((k * 4 + 1) ^ c8)];
            const float4 m2 = M[c8 * 32 + ((k * 4 + 2) ^ c8)];
            const float4 m3 = M[c8 * 32 + ((k * 4 + 3) ^ c8)];
            const float mr_[8] = {m0.x,m0.z,m1.x,m1.z,m2.x,m2.z,m3.x,m3.z};
            const float mi_[8] = {m0.y,m0.w,m1.y,m1.w,m2.y,m2.w,m3.y,m3.w};
            const float ar = pfr[k], ai = pfi[k];
#pragma unroll
            for (int c = 0; c < 8; ++c) {
                mrn[c]  += ar * mr_[c] - ai * mi_[c];
                min_[c] += ar * mi_[c] + ai * mr_[c];
            }
        }
#pragma unroll
        for (int s = 0; s < 4; ++s)
            M[c8 * 32 + ((r * 4 + s) ^ c8)] =
                make_float4(mrn[2*s], min_[2*s], mrn[2*s+1], min_[2*s+1]);
    }
    // coarse outputs
    const long rowIdx2 = ((long)s2 * 256 + n) * 8 + r;
    float4* g2 = (float4*)(sumP2 + rowIdx2 * 8);
#pragma unroll
    for (int s = 0; s < 4; ++s)
        g2[s] = make_float4(mrn[2*s], min_[2*s], mrn[2*s+1], min_[2*s+1]);
    sumQ2[rowIdx2] = make_float2(q2r[r], q2i[r]);
}

// ======== Phase 2b: scan 32 coarse summaries -> carry2 per coarse chunk ========
__global__ __launch_bounds__(64) void k_carry2(
    const float2* __restrict__ sumP2, const float2* __restrict__ sumQ2,
    float2* __restrict__ carry2)
{
    __shared__ float2 ql[64];
    const int lane = threadIdx.x;
    const int c8 = lane >> 3, r = lane & 7;
    const int n = blockIdx.x * 8 + c8;
    float yr[8], yi[8];
#pragma unroll
    for (int k = 0; k < 8; ++k) { yr[k] = 0.f; yi[k] = 0.f; }
#pragma unroll 1
    for (int s2 = 0; s2 < S2; ++s2) {
        const long rowIdx2 = ((long)s2 * 256 + n) * 8 + r;
        carry2[rowIdx2] = make_float2(yr[r], yi[r]);   // carry INTO coarse chunk s2
        const float4* gp = (const float4*)(sumP2 + rowIdx2 * 8);
        const float4 p0 = gp[0], p1 = gp[1], p2 = gp[2], p3 = gp[3];
        const float pfr[8] = {p0.x,p0.z,p1.x,p1.z,p2.x,p2.z,p3.x,p3.z};
        const float pfi[8] = {p0.y,p0.w,p1.y,p1.w,p2.y,p2.w,p3.y,p3.w};
        const float2 q2 = sumQ2[rowIdx2];
        float nr = q2.x, ni = q2.y;
#pragma unroll
        for (int k = 0; k < 8; ++k) {
            nr += pfr[k] * yr[k] - pfi[k] * yi[k];
            ni += pfr[k] * yi[k] + pfi[k] * yr[k];
        }
        ql[lane] = make_float2(nr, ni);
        const float4* qv = (const float4*)ql;
#pragma unroll
        for (int s = 0; s < 4; ++s) {
            const float4 u = qv[c8 * 4 + s];
            yr[2*s] = u.x; yi[2*s] = u.y; yr[2*s+1] = u.z; yi[2*s+1] = u.w;
        }
    }
}

// ======== Phase 3: fixup + output (chain-per-lane) ========
__global__ __launch_bounds__(64) void k_fix(
    const float* __restrict__ Are, const float* __restrict__ Aim,
    const float* __restrict__ Xre, const float* __restrict__ Xim,
    const float2* __restrict__ sumP, const float2* __restrict__ sumQ,  // prefixes
    const float2* __restrict__ carry2, float* __restrict__ out)
{
    __shared__ float4 lds[2048];
    const int lane = threadIdx.x;
    const int blk = blockIdx.x;
    const int b = blk >> 8, s1 = blk & 255;
    const int s2 = s1 >> 3;

    // ---- prologue: y = prefixM @ carry2 + prefixQ
    {
        const float4* gp = (const float4*)(sumP + ((long)s1 * 256 + b * 64) * 64);
        float4 v[16];
#pragma unroll
        for (int half = 0; half < 2; ++half) {
#pragma unroll
            for (int io = 0; io < 16; ++io) v[io] = gp[(half * 16 + io) * 64 + lane];
#pragma unroll
            for (int io = 0; io < 16; ++io) {
                const int gi = (half * 16 + io) * 64 + lane;
                lds[posPF(gi >> 5, gi & 31)] = v[io];
            }
        }
    }
    float yrr[8], yii[8];
    {
        float c2r[8], c2i[8], pqr[8], pqi[8];
        const float4* gc = (const float4*)(carry2 + ((long)s2 * 256 + b * 64 + lane) * 8);
#pragma unroll
        for (int s = 0; s < 4; ++s) {
            const float4 u = gc[s];
            c2r[2*s] = u.x; c2i[2*s] = u.y; c2r[2*s+1] = u.z; c2i[2*s+1] = u.w;
        }
        const float4* gq = (const float4*)(sumQ + ((long)s1 * 256 + b * 64 + lane) * 8);
#pragma unroll
        for (int s = 0; s < 4; ++s) {
            const float4 u = gq[s];
            pqr[2*s] = u.x; pqi[2*s] = u.y; pqr[2*s+1] = u.z; pqi[2*s+1] = u.w;
        }
#pragma unroll
        for (int r = 0; r < 8; ++r) {
            const float4 m0 = lds[posPF(lane, r * 4 + 0)];
            const float4 m1 = lds[posPF(lane, r * 4 + 1)];
            const float4 m2 = lds[posPF(lane, r * 4 + 2)];
            const float4 m3 = lds[posPF(lane, r * 4 + 3)];
            const float mr_[8] = {m0.x,m0.z,m1.x,m1.z,m2.x,m2.z,m3.x,m3.z};
            const float mi_[8] = {m0.y,m0.w,m1.y,m1.w,m2.y,m2.w,m3.y,m3.w};
            float nr = pqr[r], ni = pqi[r];
#pragma unroll
            for (int k = 0; k < 8; ++k) {
                nr += mr_[k] * c2r[k] - mi_[k] * c2i[k];
                ni += mr_[k] * c2i[k] + mi_[k] * c2r[k];
            }
            yrr[r] = nr; yii[r] = ni;
        }
    }
    // ---- main loop: y = A_t y + x_t, store each step
#pragma unroll 1
    for (int tt = 0; tt < TQ1; ++tt) {
        const int t = s1 * TQ1 + tt;
        const long fb = ((long)(b * L + t)) * C;
        {
            const float4* g0 = (const float4*)(Are + fb * 64);
            float4 v[16];
#pragma unroll
            for (int io = 0; io < 16; ++io) v[io] = g0[io * 64 + lane];
#pragma unroll
            for (int io = 0; io < 16; ++io)
                lds[posA(0, io * 4 + (lane >> 4), lane & 15)] = v[io];
            const float4* g1 = (const float4*)(Aim + fb * 64);
#pragma unroll
            for (int io = 0; io < 16; ++io) v[io] = g1[io * 64 + lane];
#pragma unroll
            for (int io = 0; io < 16; ++io)
                lds[posA(1, io * 4 + (lane >> 4), lane & 15)] = v[io];
        }
        float xr[8], xi[8];
        {
            const float4* gx = (const float4*)(Xre + fb * 8) + lane * 2;
            float4 a = gx[0], bb = gx[1];
            xr[0]=a.x; xr[1]=a.y; xr[2]=a.z; xr[3]=a.w; xr[4]=bb.x; xr[5]=bb.y; xr[6]=bb.z; xr[7]=bb.w;
            const float4* gy = (const float4*)(Xim + fb * 8) + lane * 2;
            a = gy[0]; bb = gy[1];
            xi[0]=a.x; xi[1]=a.y; xi[2]=a.z; xi[3]=a.w; xi[4]=bb.x; xi[5]=bb.y; xi[6]=bb.z; xi[7]=bb.w;
        }
        float nyr[8], nyi[8];
#pragma unroll
        for (int r = 0; r < 8; ++r) {
            const float4 e0 = lds[posA(0, lane, 2 * r)];
            const float4 e1 = lds[posA(0, lane, 2 * r + 1)];
            const float4 f0 = lds[posA(1, lane, 2 * r)];
            const float4 f1 = lds[posA(1, lane, 2 * r + 1)];
            const float are[8] = {e0.x,e0.y,e0.z,e0.w,e1.x,e1.y,e1.z,e1.w};
            const float aim[8] = {f0.x,f0.y,f0.z,f0.w,f1.x,f1.y,f1.z,f1.w};
            float nr = xr[r], ni = xi[r];
#pragma unroll
            for (int k = 0; k < 8; ++k) {
                nr += are[k] * yrr[k] - aim[k] * yii[k];
                ni += are[k] * yii[k] + aim[k] * yrr[k];
            }
            nyr[r] = nr; nyi[r] = ni;
        }
#pragma unroll
        for (int r = 0; r < 8; ++r) { yrr[r] = nyr[r]; yii[r] = nyi[r]; }
        float4* po = (float4*)(out + ((long)(b * L + t) * 64 + lane) * 16);
#pragma unroll
        for (int s = 0; s < 4; ++s)
            po[s] = make_float4(yrr[2*s], yii[2*s], yrr[2*s+1], yii[2*s+1]);
    }
}

extern "C" void kernel_launch(void* const* d_in, const int* in_sizes, int n_in,
                              void* d_out, int out_size, void* d_ws, size_t ws_size,
                              hipStream_t stream)
{
    const float* Are = (const float*)d_in[0];
    const float* Aim = (const float*)d_in[1];
    const float* Xre = (const float*)d_in[2];
    const float* Xim = (const float*)d_in[3];
    float* out = (float*)d_out;

    // workspace: 43 MB of float2
    float2* sumP   = (float2*)d_ws;                    // S1*256*64  = 4,194,304
    float2* sumQ   = sumP  + (long)S1 * 256 * 64;      // S1*256*8   =   524,288
    float2* sumP2  = sumQ  + (long)S1 * 256 * 8;       // S2*256*64  =   524,288
    float2* sumQ2  = sumP2 + (long)S2 * 256 * 64;      // S2*256*8   =    65,536
    float2* carry2 = sumQ2 + (long)S2 * 256 * 8;       // S2*256*8   =    65,536

    k_sum<<<B * S1, 64, 0, stream>>>(Are, Aim, Xre, Xim, sumP, sumQ);
    k_comb<<<S2 * 32, 64, 0, stream>>>(sumP, sumQ, sumP2, sumQ2);
    k_carry2<<<NCH / 8, 64, 0, stream>>>(sumP2, sumQ2, carry2);
    k_fix<<<B * S1, 64, 0, stream>>>(Are, Aim, Xre, Xim, sumP, sumQ, carry2, out);
}